// Round 24
// baseline (96.679 us; speedup 1.0000x reference)
//
#include <hip/hip_runtime.h>

// Problem constants
#define K_CODES 512
#define DIM 80
#define SEQ 4096
#define NVEC 131072
#define NELEM ((size_t)NVEC * DIM)
#define VPB 32                       // vectors per block: 2 waves x 1 set x 16
#define NPH 16                       // phases: 2 x 16-code tiles each
#define PH_BYTES 6144                // 2 tiles x 3072 B (hi-only B)

typedef short short8 __attribute__((ext_vector_type(8)));
typedef float f32x4 __attribute__((ext_vector_type(4)));

// ws layout: ghist[512] @0 | gsq @2048 | wsq[512] @4096 | wfrag @8192 (98304 B) | bk @204800
#define WS_GSQ   2048
#define WS_WSQ   4096
#define WS_WFRAG 8192
#define WS_BK    (8192 + 196608)

__device__ __forceinline__ unsigned short f2bf(float f) {
    union { float f; unsigned int u; } c; c.f = f;
    unsigned int r = c.u + 0x7FFFu + ((c.u >> 16) & 1u);   // RNE
    return (unsigned short)(r >> 16);
}
__device__ __forceinline__ float bf2f(unsigned short h) {
    union { float f; unsigned int u; } c; c.u = ((unsigned int)h) << 16;
    return c.f;
}

__device__ __forceinline__ void gload_lds16(const void* g, void* l) {
    __builtin_amdgcn_global_load_lds(
        (const __attribute__((address_space(1))) void*)g,
        (__attribute__((address_space(3))) void*)l, 16, 0, 0);
}

// Fused setup: wfrag (fragment-ordered HI-ONLY bf16 codebook) + wsq (row
// norms of the exact fp32 codebook).
// wfrag: [t16 0..31][g 0..2][lane 0..63] short8; g=ks; lane=(cg<<4)|cl;
//        value = bf16(weight[code=t16*16+cl][c=ks*32+cg*8 ..+8))
__global__ void vq_setup(const float* __restrict__ weight,
                         short8* __restrict__ wf, float* __restrict__ wsq)
{
    int idx = blockIdx.x * 256 + threadIdx.x;   // 24 blocks -> 6144
    if (blockIdx.x < 2) {
        int k = blockIdx.x * 256 + threadIdx.x;
        const float* w = weight + (size_t)k * DIM;
        float s = 0.f;
#pragma unroll
        for (int c = 0; c < DIM; ++c) s = fmaf(w[c], w[c], s);
        wsq[k] = s;
    }
    int t   = idx / 192;
    int rem = idx - t * 192;
    int g   = rem >> 6, l = rem & 63;   // g = ks 0..2
    int cl  = l & 15, cg = l >> 4;
    int code = t * 16 + cl;
    int c0 = g * 32 + cg * 8;
    short8 v;
#pragma unroll
    for (int j = 0; j < 8; ++j) {
        int c = c0 + j;
        unsigned short r = 0;
        if (c < DIM) r = f2bf(weight[(size_t)code * DIM + c]);
        v[j] = (short)r;
    }
    wf[idx] = v;
}

// Distance GEMM + argmin. R22 phase structure (hi-only B, 2-tile phases,
// 6-deep MFMA C-chains, stage-early/barrier-late) with 1 A-SET PER WAVE
// (VPB=32, 4096 blocks): occupancy rises from grid-capped 50% to ~69%
// (LDS-capped 11 blocks/CU x 2 waves) -- more TLP for the latency-bound loop.
__global__ __launch_bounds__(128, 8) void vq_argmin(
    const float* __restrict__ x, const short8* __restrict__ wf,
    const float* __restrict__ wsq, int* __restrict__ bk)
{
    __shared__ short8 bbuf[2][384];    // 2 x 6 KB phase buffers (2 tiles each)
    __shared__ float wsq_lds[K_CODES]; // 2 KB

    const int tid = threadIdx.x;
    *(float4*)&wsq_lds[tid * 4] = *(const float4*)&wsq[tid * 4];

    const int v0 = blockIdx.x * VPB;
    const int b  = v0 >> 12;
    const int l0 = v0 & 4095;
    const float* xbase = x + (size_t)b * DIM * SEQ + l0;

    const int lane = tid & 63, wid = tid >> 6;
    const int cg = lane >> 4;          // k-group 0..3
    const int cl = lane & 15;          // A row / B col
    const int ar = wid * 16 + cl;      // this wave's local vector

    // ---- stage phase 0 (tiles 0,1): 3 x 16B per thread, linear ----
    {
        const char* src = (const char*)wf + tid * 16;
        char* dst = (char*)&bbuf[0][0] + tid * 16;
        gload_lds16(src, dst);
        gload_lds16(src + 2048, dst + 2048);
        gload_lds16(src + 4096, dst + 4096);
    }

    // ---- A fragments (1 set, hi/lo), direct from global ----
    short8 ahi[3], alo[3];
#pragma unroll
    for (int ks = 0; ks < 3; ++ks) {
#pragma unroll
        for (int j = 0; j < 8; ++j) {
            int c = ks * 32 + cg * 8 + j;
            unsigned short hb = 0, lb = 0;
            if (c < DIM) {
                float f = xbase[(size_t)c * SEQ + ar];
                hb = f2bf(f);
                lb = f2bf(f - bf2f(hb));
            }
            ahi[ks][j] = (short)hb;
            alo[ks][j] = (short)lb;
        }
    }

    float bestd[4];
    int   bestk[4];
#pragma unroll
    for (int r = 0; r < 4; ++r) { bestd[r] = 3.4028235e38f; bestk[r] = 0; }

    __syncthreads();   // phase-0 staging drained; wsq_lds visible

    for (int ph = 0; ph < NPH; ++ph) {
        // stage next phase's 2 tiles FIRST -- overlaps both half-computes,
        // drained at the end-of-phase barrier. Target buffer's readers
        // (phase ph-1) finished at the previous barrier.
        if (ph + 1 < NPH) {
            const char* src = (const char*)wf + (size_t)(ph + 1) * PH_BYTES + tid * 16;
            char* dst = (char*)&bbuf[(ph + 1) & 1][0] + tid * 16;
            gload_lds16(src, dst);
            gload_lds16(src + 2048, dst + 2048);
            gload_lds16(src + 4096, dst + 4096);
        }

#pragma unroll
        for (int h = 0; h < 2; ++h) {
            const short8* bb = &bbuf[ph & 1][h * 192];
            short8 bh0 = bb[lane];
            short8 bh1 = bb[64 + lane];
            short8 bh2 = bb[128 + lane];
            float wv = wsq_lds[ph * 32 + h * 16 + cl];

            f32x4 acc = {0.f, 0.f, 0.f, 0.f};
            __builtin_amdgcn_s_setprio(1);
            // 6-deep C-chain: hh0,hh1,hh2,lh0,lh1,lh2 = x . bf16(w)
            acc = __builtin_amdgcn_mfma_f32_16x16x32_bf16(ahi[0], bh0, acc, 0, 0, 0);
            acc = __builtin_amdgcn_mfma_f32_16x16x32_bf16(ahi[1], bh1, acc, 0, 0, 0);
            acc = __builtin_amdgcn_mfma_f32_16x16x32_bf16(ahi[2], bh2, acc, 0, 0, 0);
            acc = __builtin_amdgcn_mfma_f32_16x16x32_bf16(alo[0], bh0, acc, 0, 0, 0);
            acc = __builtin_amdgcn_mfma_f32_16x16x32_bf16(alo[1], bh1, acc, 0, 0, 0);
            acc = __builtin_amdgcn_mfma_f32_16x16x32_bf16(alo[2], bh2, acc, 0, 0, 0);
            __builtin_amdgcn_s_setprio(0);

            const int code = ph * 32 + h * 16 + cl;
#pragma unroll
            for (int r = 0; r < 4; ++r) {
                float q = fmaf(-2.f, acc[r], wv);
                if (q < bestd[r]) { bestd[r] = q; bestk[r] = code; }
            }
        }

        __syncthreads();   // drains next-phase staging; all reads of bbuf[ph&1] done
    }

    // ---- cross-lane argmin over 16-code column groups (lexicographic) ----
#pragma unroll
    for (int r = 0; r < 4; ++r) {
        float d = bestd[r]; int k = bestk[r];
#pragma unroll
        for (int off = 1; off < 16; off <<= 1) {
            float od = __shfl_xor(d, off, 64);
            int   ok = __shfl_xor(k, off, 64);
            if (od < d || (od == d && ok < k)) { d = od; k = ok; }
        }
        if (cl == 0) {
            int vloc = wid * 16 + cg * 4 + r;    // D row = (lane>>4)*4 + reg
            bk[v0 + vloc] = k;
        }
    }
}

// Memory-bound epilogue: thread = vector. Row-gather codebook (exact fp32),
// coalesced x reads / out writes, loss + histogram.
__global__ __launch_bounds__(256) void vq_epilogue(
    const float* __restrict__ x, const float* __restrict__ weight,
    const int* __restrict__ bk, float* __restrict__ out,
    float* __restrict__ gsq, int* __restrict__ ghist)
{
    __shared__ float lsum[4];
    __shared__ int lhist[K_CODES];
    const int tid = threadIdx.x;
    for (int i = tid; i < K_CODES; i += 256) lhist[i] = 0;
    __syncthreads();

    const int v = blockIdx.x * 256 + tid;
    const int b = v >> 12;
    const int l = v & 4095;
    const int kk = bk[v];
    atomicAdd(&lhist[kk], 1);

    const float* xp = x + (size_t)b * DIM * SEQ + l;
    const float* wr = weight + (size_t)kk * DIM;
    float* op = out + 1 + (size_t)b * DIM * SEQ + l;

    float sq = 0.f;
#pragma unroll
    for (int c = 0; c < DIM; c += 4) {
        float4 wv = *(const float4*)(wr + c);
        float x0 = xp[(size_t)(c + 0) * SEQ];
        float x1 = xp[(size_t)(c + 1) * SEQ];
        float x2 = xp[(size_t)(c + 2) * SEQ];
        float x3 = xp[(size_t)(c + 3) * SEQ];
        float e0 = wv.x - x0, e1 = wv.y - x1, e2 = wv.z - x2, e3 = wv.w - x3;
        sq = fmaf(e0, e0, sq);
        sq = fmaf(e1, e1, sq);
        sq = fmaf(e2, e2, sq);
        sq = fmaf(e3, e3, sq);
        op[(size_t)(c + 0) * SEQ] = wv.x;
        op[(size_t)(c + 1) * SEQ] = wv.y;
        op[(size_t)(c + 2) * SEQ] = wv.z;
        op[(size_t)(c + 3) * SEQ] = wv.w;
    }

#pragma unroll
    for (int off = 32; off; off >>= 1) sq += __shfl_down(sq, off, 64);
    if ((tid & 63) == 0) lsum[tid >> 6] = sq;
    __syncthreads();
    if (tid == 0) {
        float s = lsum[0] + lsum[1] + lsum[2] + lsum[3];
        atomicAdd(gsq, s);
    }
    for (int i = tid; i < K_CODES; i += 256) {
        int cnt = lhist[i];
        if (cnt) atomicAdd(&ghist[i], cnt);
    }
}

__global__ void vq_finalize(const int* __restrict__ hist,
                            const float* __restrict__ gsq,
                            float* __restrict__ out, int out_last)
{
    __shared__ float part[8];
    int t = threadIdx.x;  // 512 threads
    float p = (float)hist[t] * (1.0f / (float)NVEC);
    float term = p * logf(p + 1e-10f);
#pragma unroll
    for (int off = 32; off; off >>= 1) term += __shfl_down(term, off, 64);
    if ((t & 63) == 0) part[t >> 6] = term;
    __syncthreads();
    if (t == 0) {
        float s = 0.f;
#pragma unroll
        for (int i = 0; i < 8; ++i) s += part[i];
        out[out_last] = expf(-s);
        out[0] = 1.25f * gsq[0] / (float)NELEM;
    }
}

extern "C" void kernel_launch(void* const* d_in, const int* in_sizes, int n_in,
                              void* d_out, int out_size, void* d_ws, size_t ws_size,
                              hipStream_t stream) {
    const float* x = (const float*)d_in[0];
    const float* weight = (const float*)d_in[1];
    float* out = (float*)d_out;

    int* ghist = (int*)d_ws;
    float* gsq = (float*)((char*)d_ws + WS_GSQ);
    float* wsq = (float*)((char*)d_ws + WS_WSQ);
    short8* wf = (short8*)((char*)d_ws + WS_WFRAG);
    int* bk = (int*)((char*)d_ws + WS_BK);

    hipMemsetAsync(d_ws, 0, 2052, stream);

    vq_setup<<<24, 256, 0, stream>>>(weight, wf, wsq);
    vq_argmin<<<NVEC / VPB, 128, 0, stream>>>(x, wf, wsq, bk);
    vq_epilogue<<<NVEC / 256, 256, 0, stream>>>(x, weight, bk, out, gsq, ghist);
    vq_finalize<<<1, K_CODES, 0, stream>>>(ghist, gsq, out, out_size - 1);
}

// Round 25
// 72.132 us; speedup vs baseline: 1.3403x; 1.3403x over previous
//
#include <hip/hip_runtime.h>

// Problem constants
#define K_CODES 512
#define DIM 80
#define SEQ 4096
#define NVEC 131072
#define NELEM ((size_t)NVEC * DIM)
#define VPB 64                       // vectors per block: 2 waves x 2 sets x 16
#define NPH 16                       // phases: 2 x 16-code tiles each
#define PH_BYTES 6144                // 2 tiles x 3072 B (hi-only B)

typedef short short8 __attribute__((ext_vector_type(8)));
typedef float f32x4 __attribute__((ext_vector_type(4)));

// ws layout: ghist[512] @0 | gsq @2048 | wsq[512] @4096 | wfrag @8192 (98304 B) | bk @204800
#define WS_GSQ   2048
#define WS_WSQ   4096
#define WS_WFRAG 8192
#define WS_BK    (8192 + 196608)

__device__ __forceinline__ unsigned short f2bf(float f) {
    union { float f; unsigned int u; } c; c.f = f;
    unsigned int r = c.u + 0x7FFFu + ((c.u >> 16) & 1u);   // RNE
    return (unsigned short)(r >> 16);
}
__device__ __forceinline__ float bf2f(unsigned short h) {
    union { float f; unsigned int u; } c; c.u = ((unsigned int)h) << 16;
    return c.f;
}

__device__ __forceinline__ void gload_lds16(const void* g, void* l) {
    __builtin_amdgcn_global_load_lds(
        (const __attribute__((address_space(1))) void*)g,
        (__attribute__((address_space(3))) void*)l, 16, 0, 0);
}

// Fused setup: wfrag (fragment-ordered HI-ONLY bf16 codebook) + wsq (row
// norms of the exact fp32 codebook).
// wfrag: [t16 0..31][g 0..2][lane 0..63] short8; g=ks; lane=(cg<<4)|cl;
//        value = bf16(weight[code=t16*16+cl][c=ks*32+cg*8 ..+8))
__global__ void vq_setup(const float* __restrict__ weight,
                         short8* __restrict__ wf, float* __restrict__ wsq)
{
    int idx = blockIdx.x * 256 + threadIdx.x;   // 24 blocks -> 6144
    if (blockIdx.x < 2) {
        int k = blockIdx.x * 256 + threadIdx.x;
        const float* w = weight + (size_t)k * DIM;
        float s = 0.f;
#pragma unroll
        for (int c = 0; c < DIM; ++c) s = fmaf(w[c], w[c], s);
        wsq[k] = s;
    }
    int t   = idx / 192;
    int rem = idx - t * 192;
    int g   = rem >> 6, l = rem & 63;   // g = ks 0..2
    int cl  = l & 15, cg = l >> 4;
    int code = t * 16 + cl;
    int c0 = g * 32 + cg * 8;
    short8 v;
#pragma unroll
    for (int j = 0; j < 8; ++j) {
        int c = c0 + j;
        unsigned short r = 0;
        if (c < DIM) r = f2bf(weight[(size_t)code * DIM + c]);
        v[j] = (short)r;
    }
    wf[idx] = v;
}

// Distance GEMM + argmin. Verified-optimal configuration (R22): hi-only B
// (dot = (hi_x+lo_x).hi_w = x . bf16(w) exactly), 2 A-sets/wave, 2-wave
// blocks, 6-deep MFMA C-chains, TWO 16-code tiles per barrier phase with
// stage-early/barrier-late. All single-axis perturbations measured worse.
__global__ __launch_bounds__(128, 4) void vq_argmin(
    const float* __restrict__ x, const short8* __restrict__ wf,
    const float* __restrict__ wsq, int* __restrict__ bk)
{
    __shared__ short8 bbuf[2][384];    // 2 x 6 KB phase buffers (2 tiles each)
    __shared__ float wsq_lds[K_CODES]; // 2 KB

    const int tid = threadIdx.x;
    *(float4*)&wsq_lds[tid * 4] = *(const float4*)&wsq[tid * 4];

    const int v0 = blockIdx.x * VPB;
    const int b  = v0 >> 12;
    const int l0 = v0 & 4095;
    const float* xbase = x + (size_t)b * DIM * SEQ + l0;

    const int lane = tid & 63, wid = tid >> 6;
    const int cg = lane >> 4;          // k-group 0..3
    const int cl = lane & 15;          // A row / B col
    const int ar0 = wid * 32 + cl;     // set-0 local vector
    const int ar1 = ar0 + 16;          // set-1

    // ---- stage phase 0 (tiles 0,1): 3 x 16B per thread, linear ----
    {
        const char* src = (const char*)wf + tid * 16;
        char* dst = (char*)&bbuf[0][0] + tid * 16;
        gload_lds16(src, dst);
        gload_lds16(src + 2048, dst + 2048);
        gload_lds16(src + 4096, dst + 4096);
    }

    // ---- A fragments (2 sets, hi/lo), direct from global ----
    short8 ahi0[3], alo0[3], ahi1[3], alo1[3];
#pragma unroll
    for (int ks = 0; ks < 3; ++ks) {
#pragma unroll
        for (int j = 0; j < 8; ++j) {
            int c = ks * 32 + cg * 8 + j;
            unsigned short h0 = 0, p0 = 0, h1 = 0, p1 = 0;
            if (c < DIM) {
                float f0 = xbase[(size_t)c * SEQ + ar0];
                float f1 = xbase[(size_t)c * SEQ + ar1];
                h0 = f2bf(f0); p0 = f2bf(f0 - bf2f(h0));
                h1 = f2bf(f1); p1 = f2bf(f1 - bf2f(h1));
            }
            ahi0[ks][j] = (short)h0; alo0[ks][j] = (short)p0;
            ahi1[ks][j] = (short)h1; alo1[ks][j] = (short)p1;
        }
    }

    float bestd[2][4];
    int   bestk[2][4];
#pragma unroll
    for (int s = 0; s < 2; ++s)
#pragma unroll
        for (int r = 0; r < 4; ++r) { bestd[s][r] = 3.4028235e38f; bestk[s][r] = 0; }

    __syncthreads();   // phase-0 staging drained; wsq_lds visible

    for (int ph = 0; ph < NPH; ++ph) {
        // stage next phase's 2 tiles FIRST -- overlaps both half-computes,
        // drained at the end-of-phase barrier. Target buffer's readers
        // (phase ph-1) finished at the previous barrier.
        if (ph + 1 < NPH) {
            const char* src = (const char*)wf + (size_t)(ph + 1) * PH_BYTES + tid * 16;
            char* dst = (char*)&bbuf[(ph + 1) & 1][0] + tid * 16;
            gload_lds16(src, dst);
            gload_lds16(src + 2048, dst + 2048);
            gload_lds16(src + 4096, dst + 4096);
        }

#pragma unroll
        for (int h = 0; h < 2; ++h) {
            const short8* bb = &bbuf[ph & 1][h * 192];
            short8 bh0 = bb[lane];
            short8 bh1 = bb[64 + lane];
            short8 bh2 = bb[128 + lane];
            float wv = wsq_lds[ph * 32 + h * 16 + cl];

            f32x4 acc0 = {0.f,0.f,0.f,0.f}, acc1 = {0.f,0.f,0.f,0.f};
            __builtin_amdgcn_s_setprio(1);
            // 6-deep C-chain per set: hh0,hh1,hh2,lh0,lh1,lh2 = x . bf16(w)
            acc0 = __builtin_amdgcn_mfma_f32_16x16x32_bf16(ahi0[0], bh0, acc0, 0, 0, 0);
            acc1 = __builtin_amdgcn_mfma_f32_16x16x32_bf16(ahi1[0], bh0, acc1, 0, 0, 0);
            acc0 = __builtin_amdgcn_mfma_f32_16x16x32_bf16(ahi0[1], bh1, acc0, 0, 0, 0);
            acc1 = __builtin_amdgcn_mfma_f32_16x16x32_bf16(ahi1[1], bh1, acc1, 0, 0, 0);
            acc0 = __builtin_amdgcn_mfma_f32_16x16x32_bf16(ahi0[2], bh2, acc0, 0, 0, 0);
            acc1 = __builtin_amdgcn_mfma_f32_16x16x32_bf16(ahi1[2], bh2, acc1, 0, 0, 0);
            acc0 = __builtin_amdgcn_mfma_f32_16x16x32_bf16(alo0[0], bh0, acc0, 0, 0, 0);
            acc1 = __builtin_amdgcn_mfma_f32_16x16x32_bf16(alo1[0], bh0, acc1, 0, 0, 0);
            acc0 = __builtin_amdgcn_mfma_f32_16x16x32_bf16(alo0[1], bh1, acc0, 0, 0, 0);
            acc1 = __builtin_amdgcn_mfma_f32_16x16x32_bf16(alo1[1], bh1, acc1, 0, 0, 0);
            acc0 = __builtin_amdgcn_mfma_f32_16x16x32_bf16(alo0[2], bh2, acc0, 0, 0, 0);
            acc1 = __builtin_amdgcn_mfma_f32_16x16x32_bf16(alo1[2], bh2, acc1, 0, 0, 0);
            __builtin_amdgcn_s_setprio(0);

            const int code = ph * 32 + h * 16 + cl;
#pragma unroll
            for (int r = 0; r < 4; ++r) {
                float q0 = fmaf(-2.f, acc0[r], wv);
                if (q0 < bestd[0][r]) { bestd[0][r] = q0; bestk[0][r] = code; }
                float q1 = fmaf(-2.f, acc1[r], wv);
                if (q1 < bestd[1][r]) { bestd[1][r] = q1; bestk[1][r] = code; }
            }
        }

        __syncthreads();   // drains next-phase staging; all reads of bbuf[ph&1] done
    }

    // ---- cross-lane argmin over 16-code column groups (lexicographic) ----
#pragma unroll
    for (int s = 0; s < 2; ++s) {
#pragma unroll
        for (int r = 0; r < 4; ++r) {
            float d = bestd[s][r]; int k = bestk[s][r];
#pragma unroll
            for (int off = 1; off < 16; off <<= 1) {
                float od = __shfl_xor(d, off, 64);
                int   ok = __shfl_xor(k, off, 64);
                if (od < d || (od == d && ok < k)) { d = od; k = ok; }
            }
            if (cl == 0) {
                int vloc = wid * 32 + s * 16 + cg * 4 + r;   // D row=(lane>>4)*4+reg
                bk[v0 + vloc] = k;
            }
        }
    }
}

// Memory-bound epilogue: thread = vector. Row-gather codebook (exact fp32),
// coalesced x reads / out writes, loss + histogram.
__global__ __launch_bounds__(256) void vq_epilogue(
    const float* __restrict__ x, const float* __restrict__ weight,
    const int* __restrict__ bk, float* __restrict__ out,
    float* __restrict__ gsq, int* __restrict__ ghist)
{
    __shared__ float lsum[4];
    __shared__ int lhist[K_CODES];
    const int tid = threadIdx.x;
    for (int i = tid; i < K_CODES; i += 256) lhist[i] = 0;
    __syncthreads();

    const int v = blockIdx.x * 256 + tid;
    const int b = v >> 12;
    const int l = v & 4095;
    const int kk = bk[v];
    atomicAdd(&lhist[kk], 1);

    const float* xp = x + (size_t)b * DIM * SEQ + l;
    const float* wr = weight + (size_t)kk * DIM;
    float* op = out + 1 + (size_t)b * DIM * SEQ + l;

    float sq = 0.f;
#pragma unroll
    for (int c = 0; c < DIM; c += 4) {
        float4 wv = *(const float4*)(wr + c);
        float x0 = xp[(size_t)(c + 0) * SEQ];
        float x1 = xp[(size_t)(c + 1) * SEQ];
        float x2 = xp[(size_t)(c + 2) * SEQ];
        float x3 = xp[(size_t)(c + 3) * SEQ];
        float e0 = wv.x - x0, e1 = wv.y - x1, e2 = wv.z - x2, e3 = wv.w - x3;
        sq = fmaf(e0, e0, sq);
        sq = fmaf(e1, e1, sq);
        sq = fmaf(e2, e2, sq);
        sq = fmaf(e3, e3, sq);
        op[(size_t)(c + 0) * SEQ] = wv.x;
        op[(size_t)(c + 1) * SEQ] = wv.y;
        op[(size_t)(c + 2) * SEQ] = wv.z;
        op[(size_t)(c + 3) * SEQ] = wv.w;
    }

#pragma unroll
    for (int off = 32; off; off >>= 1) sq += __shfl_down(sq, off, 64);
    if ((tid & 63) == 0) lsum[tid >> 6] = sq;
    __syncthreads();
    if (tid == 0) {
        float s = lsum[0] + lsum[1] + lsum[2] + lsum[3];
        atomicAdd(gsq, s);
    }
    for (int i = tid; i < K_CODES; i += 256) {
        int cnt = lhist[i];
        if (cnt) atomicAdd(&ghist[i], cnt);
    }
}

__global__ void vq_finalize(const int* __restrict__ hist,
                            const float* __restrict__ gsq,
                            float* __restrict__ out, int out_last)
{
    __shared__ float part[8];
    int t = threadIdx.x;  // 512 threads
    float p = (float)hist[t] * (1.0f / (float)NVEC);
    float term = p * logf(p + 1e-10f);
#pragma unroll
    for (int off = 32; off; off >>= 1) term += __shfl_down(term, off, 64);
    if ((t & 63) == 0) part[t >> 6] = term;
    __syncthreads();
    if (t == 0) {
        float s = 0.f;
#pragma unroll
        for (int i = 0; i < 8; ++i) s += part[i];
        out[out_last] = expf(-s);
        out[0] = 1.25f * gsq[0] / (float)NELEM;
    }
}

extern "C" void kernel_launch(void* const* d_in, const int* in_sizes, int n_in,
                              void* d_out, int out_size, void* d_ws, size_t ws_size,
                              hipStream_t stream) {
    const float* x = (const float*)d_in[0];
    const float* weight = (const float*)d_in[1];
    float* out = (float*)d_out;

    int* ghist = (int*)d_ws;
    float* gsq = (float*)((char*)d_ws + WS_GSQ);
    float* wsq = (float*)((char*)d_ws + WS_WSQ);
    short8* wf = (short8*)((char*)d_ws + WS_WFRAG);
    int* bk = (int*)((char*)d_ws + WS_BK);

    hipMemsetAsync(d_ws, 0, 2052, stream);

    vq_setup<<<24, 256, 0, stream>>>(weight, wf, wsq);
    vq_argmin<<<NVEC / VPB, 128, 0, stream>>>(x, wf, wsq, bk);
    vq_epilogue<<<NVEC / 256, 256, 0, stream>>>(x, weight, bk, out, gsq, ghist);
    vq_finalize<<<1, K_CODES, 0, stream>>>(ghist, gsq, out, out_size - 1);
}